// Round 9
// baseline (2757.484 us; speedup 1.0000x reference)
//
#include <hip/hip_runtime.h>
#include <math.h>
#include <stdint.h>

typedef _Float16 f16;
typedef _Float16 f16x8 __attribute__((ext_vector_type(8)));
typedef float f32x4 __attribute__((ext_vector_type(4)));
typedef unsigned short u16;
typedef u16 u16x8 __attribute__((ext_vector_type(8)));

#define HID 256
#define K1ACT 3202
#define NS1 101               // ceil(3202/32), padded K = 3232
#define NS2 8                 // 256/32
#define NPX 65536
#define BPX 64
#define NBLK (NPX/BPX)        // 1024 (layers 2/3)
#define PXB_TOTAL 512         // layer-1 128-px blocks

// ws layout (bytes)
#define OFF_W1 0
#define SZ_W1  ((size_t)NS1*32768)
#define OFF_W2 SZ_W1
#define SZ_W2  ((size_t)NS2*32768)
#define OFF_W3 (OFF_W2+SZ_W2)
#define OFF_H  ((size_t)4194304)
#define SZ_H   ((size_t)NPX*HID*4)          // 64 MB
#define OFF_APACK (OFF_H + SZ_H)            // 71,303,168

__device__ inline void split2(float v, u16& h, u16& l){
  f16 hv = (f16)v;
  f16 lv = (f16)(v - (float)hv);
  h = __builtin_bit_cast(u16, hv);
  l = __builtin_bit_cast(u16, lv);
}

// Pre-split W (fp32 [K][256]) into fp16 hi/lo MFMA-fragment units (proven r2 layout).
__global__ void prep_w(const float* __restrict__ W, int Kact, int nStages,
                       u16* __restrict__ outp){
  int t = blockIdx.x*256 + threadIdx.x;
  if (t >= nStages*1024) return;
  int s = t >> 10, r = t & 1023;
  int w = r >> 8, nf = (r >> 6) & 3, l = r & 63;
  int col = w*64 + nf*16 + (l & 15);
  int kb  = s*32 + (l >> 4)*8;
  u16x8 hv, lv;
  #pragma unroll
  for (int j = 0; j < 8; ++j){
    int k = kb + j;
    float v = (k < Kact) ? W[(size_t)k*HID + col] : 0.f;
    u16 h, lo; split2(v, h, lo);
    hv[j] = h; lv[j] = lo;
  }
  size_t U0 = ((((size_t)s*4 + w)*4 + nf)*2 + 0)*64 + l;
  *(u16x8*)(outp + U0*8)      = hv;
  *(u16x8*)(outp + (U0+64)*8) = lv;
}

// ---------------------------------------------------------------------------
// prep_a: materialize im2col(xi)+coords as fp16 hi/lo fragment-major units.
// Slab (s, pxbL) = 16 KB linear: [mf(8)][split(2)][lane(64)][8 f16].
//   lane l, elem j -> A[px = pxb*128 + mf*16 + (l&15)][k = s*32 + (l>>4)*8 + j]
// ---------------------------------------------------------------------------
__global__ __launch_bounds__(256)
void prep_a(const float* __restrict__ xi, u16* __restrict__ ap,
            int pxbBase, int pxbCount){
  int bid  = blockIdx.x;
  int s    = bid / (pxbCount*2);
  int r    = bid - s*(pxbCount*2);
  int pxbL = r >> 1;
  int half = r & 1;
  int tid  = threadIdx.x;
  int mf   = half*4 + (tid >> 6);
  int lane = tid & 63;
  int px   = (pxbBase + pxbL)*128 + mf*16 + (lane & 15);
  int y    = px >> 8, x = px & 255;
  int k0   = s*32 + (lane >> 4)*8;
  float gy = -1.f + (2.f/255.f)*(float)y;
  float gx = -1.f + (2.f/255.f)*(float)x;
  u16x8 hv, lv;
  #pragma unroll
  for (int j = 0; j < 8; ++j){
    int k = k0 + j;
    float v = 0.f;
    if (k < 3200){
      int c = k/25, rr = k - 25*c;
      int dy = rr/5, dx = rr - 5*dy;
      int yy = y + dy - 2, xx = x + dx - 2;
      if ((unsigned)yy < 256u && (unsigned)xx < 256u)
        v = xi[((size_t)c<<16) + ((size_t)yy<<8) + xx];
    } else if (k == 3200) v = gy;
    else if (k == 3201) v = gx;
    u16 h, l; split2(v, h, l); hv[j] = h; lv[j] = l;
  }
  u16* base = (u16*)((char*)ap + ((size_t)s*pxbCount + pxbL)*16384);
  *(u16x8*)(base + ((size_t)(mf*2+0)*64 + lane)*8) = hv;
  *(u16x8*)(base + ((size_t)(mf*2+1)*64 + lane)*8) = lv;
}

// ---------------------------------------------------------------------------
// Layer-1 GEMM from pre-materialized A: pure m97 structure.
// 128px x 128col per block, 256 thr = 4 waves (wave = 64x64, 48 MFMA/step).
// Per step: 4+4 linear global_load_lds, barrier, ds_read frags + MFMA, barrier.
// ---------------------------------------------------------------------------
__global__ __launch_bounds__(256, 3)
void gemm_l1p(const u16* __restrict__ Ap, const u16* __restrict__ Wp,
              const float* __restrict__ bias, uint32_t* __restrict__ hout,
              int pxbBase, int pxbCount, int nt){
  __shared__ __align__(16) u16 Ab[8192];   // 16 KB: [mfb(8)][split(2)][lane(64)][8]
  __shared__ __align__(16) u16 Bb[8192];   // 16 KB: [g(8)][split(2)][lane(64)][8]

  const int tid  = threadIdx.x;
  const int lane = tid & 63;
  const int wv   = tid >> 6;
  const int wm   = wv >> 1, wn = wv & 1;

  const int G = gridDim.x;                 // multiple of 8
  int bid = blockIdx.x;
  bid = (bid & 7)*(G >> 3) + (bid >> 3);   // XCD-chunked swizzle
  const int pxbL = bid >> 1;
  const int ch   = bid & 1;

  f32x4 acc[4][4];
  #pragma unroll
  for (int a=0;a<4;a++)
    #pragma unroll
    for (int b=0;b<4;b++) acc[a][b] = f32x4{0.f,0.f,0.f,0.f};

  for (int t = 0; t < nt; ++t){
    const char* sa = (const char*)Ap + ((size_t)t*pxbCount + pxbL)*16384 + tid*16;
    char* da = (char*)&Ab[0] + tid*16;
    #pragma unroll
    for (int i=0;i<4;++i)
      __builtin_amdgcn_global_load_lds(
        (const __attribute__((address_space(1))) uint32_t*)(sa + i*4096),
        (__attribute__((address_space(3))) uint32_t*)(da + i*4096), 16, 0, 0);
    const char* sb = (const char*)Wp + (size_t)t*32768 + (size_t)ch*16384 + tid*16;
    char* db = (char*)&Bb[0] + tid*16;
    #pragma unroll
    for (int i=0;i<4;++i)
      __builtin_amdgcn_global_load_lds(
        (const __attribute__((address_space(1))) uint32_t*)(sb + i*4096),
        (__attribute__((address_space(3))) uint32_t*)(db + i*4096), 16, 0, 0);
    __syncthreads();                       // barrier 1: staging visible

    f16x8 ah[4], al[4];
    #pragma unroll
    for (int mf=0;mf<4;++mf){
      ah[mf] = *(const f16x8*)(&Ab[((size_t)((wm*4+mf)*2+0)*64 + lane)*8]);
      al[mf] = *(const f16x8*)(&Ab[((size_t)((wm*4+mf)*2+1)*64 + lane)*8]);
    }
    __builtin_amdgcn_s_setprio(1);
    #pragma unroll
    for (int nf=0;nf<4;++nf){
      f16x8 bh = *(const f16x8*)(&Bb[((size_t)((wn*4+nf)*2+0)*64 + lane)*8]);
      f16x8 bl = *(const f16x8*)(&Bb[((size_t)((wn*4+nf)*2+1)*64 + lane)*8]);
      #pragma unroll
      for (int mf=0;mf<4;++mf){
        acc[mf][nf] = __builtin_amdgcn_mfma_f32_16x16x32_f16(ah[mf], bh, acc[mf][nf], 0,0,0);
        acc[mf][nf] = __builtin_amdgcn_mfma_f32_16x16x32_f16(al[mf], bh, acc[mf][nf], 0,0,0);
        acc[mf][nf] = __builtin_amdgcn_mfma_f32_16x16x32_f16(ah[mf], bl, acc[mf][nf], 0,0,0);
      }
    }
    __builtin_amdgcn_s_setprio(0);
    __syncthreads();                       // barrier 2: LDS consumed
  }

  float bcol[4];
  #pragma unroll
  for (int nf=0;nf<4;++nf) bcol[nf] = bias[ch*128 + wn*64 + nf*16 + (lane&15)];
  const int px0 = (pxbBase + pxbL)*128;
  #pragma unroll
  for (int mf=0;mf<4;++mf)
    #pragma unroll
    for (int nf=0;nf<4;++nf)
      #pragma unroll
      for (int j=0;j<4;++j){
        float z = acc[mf][nf][j] + bcol[nf];
        float h = sinf(30.f*z);
        u16 hh,ll; split2(h,hh,ll);
        int row = wm*64 + mf*16 + (lane>>4)*4 + j;
        int col = ch*128 + wn*64 + nf*16 + (lane&15);
        hout[(size_t)(px0+row)*HID + col] = (uint32_t)hh | ((uint32_t)ll<<16);
      }
}

// ---------------------------------------------------------------------------
// Fallback fused layer-1 (r7, proven) — used only if ws too small.
// ---------------------------------------------------------------------------
__global__ __launch_bounds__(512, 2)
void gemm_l1(const float* __restrict__ xi, const u16* __restrict__ Wp,
             const float* __restrict__ bias, uint32_t* __restrict__ hout, int nt)
{
  __shared__ __align__(16) u16 Ab[2][16384];
  __shared__ __align__(16) u16 Bb[2][16384];

  const int tid  = threadIdx.x;
  const int lane = tid & 63;
  const int wv   = tid >> 6;
  const int wm   = wv >> 2, wn = wv & 3;
  const int y    = blockIdx.x;
  const int oct  = wv >> 1;
  const int pxv  = (wv & 1)*64 + lane;

  const float gy  = -1.f + (2.f/255.f)*(float)y;
  const float gx0 = -1.f + (2.f/255.f)*(float)pxv;
  const float gx1 = -1.f + (2.f/255.f)*(float)(pxv + 128);

  float fa[16];
  f32x4 acc[8][4];
  #pragma unroll
  for (int a=0;a<8;a++)
    #pragma unroll
    for (int b=0;b<4;b++) acc[a][b] = f32x4{0.f,0.f,0.f,0.f};

#define L1_ALOAD(S) do{ \
  _Pragma("unroll") \
  for (int j=0;j<8;++j){ \
    int k = (S)*32 + oct*8 + j; \
    float v0=0.f, v1=0.f; \
    if (k < 3200){ \
      int c = k/25, rr = k - 25*c; \
      int dy = rr/5, dx = rr - dy*5; \
      int yy = y + dy - 2; \
      if ((unsigned)yy < 256u){ \
        const float* _row = xi + ((size_t)c<<16) + ((size_t)yy<<8); \
        int xx0 = pxv + dx - 2; \
        int xx1 = xx0 + 128; \
        if ((unsigned)xx0 < 256u) v0 = _row[xx0]; \
        if ((unsigned)xx1 < 256u) v1 = _row[xx1]; \
      } \
    } else if (k == 3200){ v0 = gy;  v1 = gy;  } \
    else if (k == 3201){ v0 = gx0; v1 = gx1; } \
    fa[j] = v0; fa[8+j] = v1; \
  }}while(0)

#define L1_AWRITE(BUF) do{ \
  _Pragma("unroll") \
  for (int hf=0; hf<2; ++hf){ \
    u16x8 hv, lv; \
    _Pragma("unroll") \
    for (int j=0;j<8;++j){ u16 h,l; split2(fa[hf*8+j],h,l); hv[j]=h; lv[j]=l; } \
    int mfb = hf*8 + (wv&1)*4 + (lane>>4); \
    int e   = (oct*16 + (lane&15))*8; \
    *(u16x8*)(&Ab[BUF][(size_t)(mfb*2+0)*512 + e]) = hv; \
    *(u16x8*)(&Ab[BUF][(size_t)(mfb*2+1)*512 + e]) = lv; \
  }}while(0)

#define L1_BSTAGE(S,BUF) do{ \
  const char* _s = (const char*)Wp + (size_t)(S)*32768 + tid*16; \
  char* _d = (char*)&Bb[BUF][0] + tid*16; \
  _Pragma("unroll") \
  for (int i=0;i<4;++i) \
    __builtin_amdgcn_global_load_lds( \
      (const __attribute__((address_space(1))) uint32_t*)(_s + i*8192), \
      (__attribute__((address_space(3))) uint32_t*)(_d + i*8192), 16, 0, 0); \
 }while(0)

  L1_ALOAD(0);
  L1_AWRITE(0);
  L1_ALOAD(1);
  L1_BSTAGE(0, 0);
  __syncthreads();

  int cur = 0;
  for (int t = 0; t < nt; ++t){
    const int nxt = cur ^ 1;
    if (t+1 < nt){
      L1_AWRITE(nxt);
      L1_BSTAGE(t+1, nxt);
    }
    if (t+2 < nt) L1_ALOAD(t+2);

    f16x8 bh[4], bl[4];
    #pragma unroll
    for (int nf=0;nf<4;++nf){
      bh[nf] = *(const f16x8*)(&Bb[cur][(size_t)((wn*4+nf)*2+0)*512 + lane*8]);
      bl[nf] = *(const f16x8*)(&Bb[cur][(size_t)((wn*4+nf)*2+1)*512 + lane*8]);
    }
    __builtin_amdgcn_s_setprio(1);
    #pragma unroll
    for (int hf=0; hf<2; ++hf){
      f16x8 ah[4], al[4];
      #pragma unroll
      for (int m2=0;m2<4;++m2){
        int mfb = wm*8 + hf*4 + m2;
        ah[m2] = *(const f16x8*)(&Ab[cur][(size_t)(mfb*2+0)*512 + lane*8]);
        al[m2] = *(const f16x8*)(&Ab[cur][(size_t)(mfb*2+1)*512 + lane*8]);
      }
      #pragma unroll
      for (int nf=0;nf<4;++nf){
        #pragma unroll
        for (int m2=0;m2<4;++m2){
          acc[hf*4+m2][nf] = __builtin_amdgcn_mfma_f32_16x16x32_f16(ah[m2], bh[nf], acc[hf*4+m2][nf], 0,0,0);
          acc[hf*4+m2][nf] = __builtin_amdgcn_mfma_f32_16x16x32_f16(al[m2], bh[nf], acc[hf*4+m2][nf], 0,0,0);
          acc[hf*4+m2][nf] = __builtin_amdgcn_mfma_f32_16x16x32_f16(ah[m2], bl[nf], acc[hf*4+m2][nf], 0,0,0);
        }
      }
    }
    __builtin_amdgcn_s_setprio(0);
    __syncthreads();
    cur = nxt;
  }

  float bcol[4];
  #pragma unroll
  for (int nf=0;nf<4;++nf) bcol[nf] = bias[wn*64 + nf*16 + (lane&15)];
  #pragma unroll
  for (int mf=0;mf<8;++mf)
    #pragma unroll
    for (int nf=0;nf<4;++nf)
      #pragma unroll
      for (int j=0;j<4;++j){
        float z = acc[mf][nf][j] + bcol[nf];
        float h = sinf(30.f*z);
        u16 hh,ll; split2(h,hh,ll);
        int row = (wm*8 + mf)*16 + (lane>>4)*4 + j;
        int col = wn*64 + nf*16 + (lane&15);
        hout[((size_t)y*256 + row)*HID + col] = (uint32_t)hh | ((uint32_t)ll<<16);
      }
#undef L1_ALOAD
#undef L1_AWRITE
#undef L1_BSTAGE
}

// ---------------------------------------------------------------------------
// Layers 2/3(+4 tail): unchanged r5/r7 structure.
// ---------------------------------------------------------------------------
template<int MODE>
__global__ __launch_bounds__(256, 2)
void gemm_layer(const uint32_t* __restrict__ hin,
                const u16* __restrict__ Wp, const float* __restrict__ bias,
                uint32_t* __restrict__ hout, const float* __restrict__ W4,
                const float* __restrict__ b4, float* __restrict__ out, int nt)
{
  __shared__ __align__(16) u16 Ab[2][4096];
  __shared__ __align__(16) u16 Bb[2][16384];

  const int tid  = threadIdx.x;
  const int lane = tid & 63;
  const int wv   = tid >> 6;

  int bid = blockIdx.x;
  bid = (bid & 7)*(NBLK/8) + (bid >> 3);
  const int pxb = bid * BPX;

  f32x4 acc[4][4];
  #pragma unroll
  for (int a=0;a<4;a++)
    #pragma unroll
    for (int b=0;b<4;b++) acc[a][b] = f32x4{0.f,0.f,0.f,0.f};

  uint32_t ua[8];

#define A_LOAD(S) do { \
    const uint32_t* hp = hin + (size_t)(pxb + lane)*HID + (S)*32 + wv*8; \
    uint4 a0 = *(const uint4*)hp; \
    uint4 a1 = *(const uint4*)(hp+4); \
    ua[0]=a0.x; ua[1]=a0.y; ua[2]=a0.z; ua[3]=a0.w; \
    ua[4]=a1.x; ua[5]=a1.y; ua[6]=a1.z; ua[7]=a1.w; \
  } while(0)

#define A_WRITE(BUF) do { \
    u16x8 hv, lv; \
    _Pragma("unroll") \
    for (int j=0;j<8;++j){ hv[j]=(u16)(ua[j]&0xffffu); lv[j]=(u16)(ua[j]>>16); } \
    int ub = ((lane>>4)*2)*64 + wv*16 + (lane&15); \
    *(u16x8*)(&Ab[BUF][(size_t)ub*8])      = hv; \
    *(u16x8*)(&Ab[BUF][(size_t)(ub+64)*8]) = lv; \
  } while(0)

#define B_STAGE(S, BUF) do { \
    const char* _src = (const char*)Wp + (size_t)(S)*32768 + wv*8192 + lane*16; \
    char* _dst = (char*)&Bb[BUF][0] + wv*8192; \
    _Pragma("unroll") \
    for (int i=0;i<8;++i) \
      __builtin_amdgcn_global_load_lds( \
        (const __attribute__((address_space(1))) uint32_t*)(_src + i*1024), \
        (__attribute__((address_space(3))) uint32_t*)(_dst + i*1024), 16, 0, 0); \
  } while(0)

  A_LOAD(0);
  B_STAGE(0, 0);
  A_WRITE(0);
  __syncthreads();

  int cur = 0;
  for (int t = 0; t < nt; ++t){
    const int nxt = cur ^ 1;
    if (t+1 < nt){
      A_LOAD(t+1);
      B_STAGE(t+1, nxt);
    }
    f16x8 ahf[4], alf[4];
    #pragma unroll
    for (int mf=0;mf<4;++mf){
      ahf[mf] = *(const f16x8*)(&Ab[cur][((size_t)((mf*2+0)*64 + lane))*8]);
      alf[mf] = *(const f16x8*)(&Ab[cur][((size_t)((mf*2+1)*64 + lane))*8]);
    }
    __builtin_amdgcn_s_setprio(1);
    #pragma unroll
    for (int nf=0;nf<4;++nf){
      f16x8 bh = *(const f16x8*)(&Bb[cur][((size_t)(((wv*4+nf)*2+0)*64 + lane))*8]);
      f16x8 bl = *(const f16x8*)(&Bb[cur][((size_t)(((wv*4+nf)*2+1)*64 + lane))*8]);
      #pragma unroll
      for (int mf=0;mf<4;++mf){
        acc[mf][nf] = __builtin_amdgcn_mfma_f32_16x16x32_f16(ahf[mf], bh, acc[mf][nf], 0,0,0);
        acc[mf][nf] = __builtin_amdgcn_mfma_f32_16x16x32_f16(alf[mf], bh, acc[mf][nf], 0,0,0);
        acc[mf][nf] = __builtin_amdgcn_mfma_f32_16x16x32_f16(ahf[mf], bl, acc[mf][nf], 0,0,0);
      }
    }
    __builtin_amdgcn_s_setprio(0);
    if (t+1 < nt) A_WRITE(nxt);
    __syncthreads();
    cur = nxt;
  }

  float bcol[4];
  #pragma unroll
  for (int nf=0;nf<4;++nf) bcol[nf] = bias[wv*64 + nf*16 + (lane&15)];

  if (MODE != 2){
    #pragma unroll
    for (int mf=0;mf<4;++mf)
      #pragma unroll
      for (int nf=0;nf<4;++nf)
        #pragma unroll
        for (int j=0;j<4;++j){
          float z = acc[mf][nf][j] + bcol[nf];
          float h = sinf(30.f*z);
          u16 hh,ll; split2(h,hh,ll);
          int row = mf*16 + (lane>>4)*4 + j;
          int col = wv*64 + nf*16 + (lane&15);
          hout[(size_t)(pxb+row)*HID + col] = (uint32_t)hh | ((uint32_t)ll<<16);
        }
  } else {
    float (*red)[64][3] = (float(*)[64][3])(void*)&Ab[0][0];
    float w4v[4][3];
    #pragma unroll
    for (int nf=0;nf<4;++nf){
      int col = wv*64 + nf*16 + (lane&15);
      w4v[nf][0]=W4[col*3+0]; w4v[nf][1]=W4[col*3+1]; w4v[nf][2]=W4[col*3+2];
    }
    #pragma unroll
    for (int mf=0;mf<4;++mf)
      #pragma unroll
      for (int j=0;j<4;++j){
        float s0=0.f,s1=0.f,s2=0.f;
        #pragma unroll
        for (int nf=0;nf<4;++nf){
          float h = sinf(30.f*(acc[mf][nf][j] + bcol[nf]));
          s0 += h*w4v[nf][0]; s1 += h*w4v[nf][1]; s2 += h*w4v[nf][2];
        }
        #pragma unroll
        for (int m=1;m<16;m<<=1){
          s0 += __shfl_xor(s0, m);
          s1 += __shfl_xor(s1, m);
          s2 += __shfl_xor(s2, m);
        }
        if ((lane & 15) == 0){
          int row = mf*16 + (lane>>4)*4 + j;
          red[wv][row][0]=s0; red[wv][row][1]=s1; red[wv][row][2]=s2;
        }
      }
    __syncthreads();
    if (tid < 192){
      int px = tid & 63, c = tid >> 6;
      float v = red[0][px][c]+red[1][px][c]+red[2][px][c]+red[3][px][c] + b4[c];
      out[(size_t)c*NPX + pxb + px] = v;
    }
  }
#undef A_LOAD
#undef A_WRITE
#undef B_STAGE
}

// ---------------------------------------------------------------------------
extern "C" void kernel_launch(void* const* d_in, const int* in_sizes, int n_in,
                              void* d_out, int out_size, void* d_ws, size_t ws_size,
                              hipStream_t stream) {
  const float* xi = (const float*)d_in[0];
  const float* W1 = (const float*)d_in[1];
  const float* b1 = (const float*)d_in[2];
  const float* W2 = (const float*)d_in[3];
  const float* b2 = (const float*)d_in[4];
  const float* W3 = (const float*)d_in[5];
  const float* b3 = (const float*)d_in[6];
  const float* W4 = (const float*)d_in[7];
  const float* b4 = (const float*)d_in[8];
  float* out = (float*)d_out;

  char* ws = (char*)d_ws;
  u16* W1p = (u16*)(ws + OFF_W1);
  u16* W2p = (u16*)(ws + OFF_W2);
  u16* W3p = (u16*)(ws + OFF_W3);
  uint32_t* h = (uint32_t*)(ws + OFF_H);
  u16* Apack  = (u16*)(ws + OFF_APACK);

  prep_w<<<NS1*4, 256, 0, stream>>>(W1, K1ACT, NS1, W1p);
  prep_w<<<NS2*4, 256, 0, stream>>>(W2, HID, NS2, W2p);
  prep_w<<<NS2*4, 256, 0, stream>>>(W3, HID, NS2, W3p);

  // pick smallest chunk count whose Apack region fits in ws (deterministic per call)
  int NC = 0;
  const int ncs[4] = {1, 2, 4, 8};
  for (int i = 0; i < 4; ++i){
    size_t need = OFF_APACK + (size_t)NS1*(PXB_TOTAL/ncs[i])*16384;
    if (ws_size >= need){ NC = ncs[i]; break; }
  }

  if (NC){
    const int PXBC = PXB_TOTAL / NC;
    for (int c = 0; c < NC; ++c){
      prep_a<<<NS1*PXBC*2, 256, 0, stream>>>(xi, Apack, c*PXBC, PXBC);
      gemm_l1p<<<PXBC*2, 256, 0, stream>>>(Apack, W1p, b1, h, c*PXBC, PXBC, NS1);
    }
  } else {
    gemm_l1<<<256, 512, 0, stream>>>(xi, W1p, b1, h, NS1);
  }

  dim3 grid(NBLK), block(256);
  gemm_layer<1><<<grid, block, 0, stream>>>(h, W2p, b2, h,
                                            nullptr, nullptr, nullptr, NS2);
  gemm_layer<2><<<grid, block, 0, stream>>>(h, W3p, b3, nullptr,
                                            W4, b4, out, NS2);
}

// Round 10
// 1347.680 us; speedup vs baseline: 2.0461x; 2.0461x over previous
//
#include <hip/hip_runtime.h>
#include <math.h>
#include <stdint.h>

typedef _Float16 f16;
typedef _Float16 f16x8 __attribute__((ext_vector_type(8)));
typedef float f32x4 __attribute__((ext_vector_type(4)));
typedef unsigned short u16;
typedef u16 u16x8 __attribute__((ext_vector_type(8)));

#define HID 256
#define NS1C 100              // layer-1 conv K-steps: 25 taps x 4 channel-groups
#define NS2 8                 // 256/32
#define NPX 65536
#define BPX 64
#define NBLK (NPX/BPX)        // 1024

// ws layout (bytes)
#define OFF_W1C 0
#define SZ_W1C  ((size_t)NS1C*32768)        // 3,276,800
#define OFF_W2  SZ_W1C
#define SZ_W2   ((size_t)NS2*32768)         // 262,144
#define OFF_W3  (OFF_W2+SZ_W2)
#define OFF_H   ((size_t)4194304)           // 4 MB
#define SZ_H    ((size_t)NPX*HID*4)         // 64 MB
#define OFF_X   (OFF_H + SZ_H)              // 71,303,168
#define SZ_X    ((size_t)128*NPX*4)         // 32 MB  (total ~100 MB; r9 proved ws >= 177 MB)

__device__ inline void split2(float v, u16& h, u16& l){
  f16 hv = (f16)v;
  f16 lv = (f16)(v - (float)hv);
  h = __builtin_bit_cast(u16, hv);
  l = __builtin_bit_cast(u16, lv);
}

// ---------------------------------------------------------------------------
// prep_w: W (fp32 [K][256]) -> fp16 hi/lo MFMA-fragment units (proven layout):
//   unit(s, w, nf, split, lane): 8 f16, j -> W[s*32 + (lane>>4)*8 + j][w*64+nf*16+(lane&15)]
//   unit offset = (((s*4 + w)*4 + nf)*2 + split)*64 + lane
// ---------------------------------------------------------------------------
__global__ void prep_w(const float* __restrict__ W, int Kact, int nStages,
                       u16* __restrict__ outp){
  int t = blockIdx.x*256 + threadIdx.x;
  if (t >= nStages*1024) return;
  int s = t >> 10, r = t & 1023;
  int w = r >> 8, nf = (r >> 6) & 3, l = r & 63;
  int col = w*64 + nf*16 + (l & 15);
  int kb  = s*32 + (l >> 4)*8;
  u16x8 hv, lv;
  #pragma unroll
  for (int j = 0; j < 8; ++j){
    int k = kb + j;
    float v = (k < Kact) ? W[(size_t)k*HID + col] : 0.f;
    u16 h, lo; split2(v, h, lo);
    hv[j] = h; lv[j] = lo;
  }
  size_t U0 = ((((size_t)s*4 + w)*4 + nf)*2 + 0)*64 + l;
  *(u16x8*)(outp + U0*8)      = hv;
  *(u16x8*)(outp + (U0+64)*8) = lv;
}

// ---------------------------------------------------------------------------
// prep_w1c: W1 rows 0..3199 reordered tap-major into 100 conv K-step slabs.
// Step s: tap = s>>2 (dy*5+dx), channel group cg = s&3.
//   row-in-step r = cg*32 + (lane>>4)*8 + j  ->  W1 row k = r*25... careful:
//   channel c = cg*32 + (lane>>4)*8 + j ; k = c*25 + tap (im2col order k=c*25+dy*5+dx).
// Same unit layout as prep_w.
// ---------------------------------------------------------------------------
__global__ void prep_w1c(const float* __restrict__ W1, u16* __restrict__ outp){
  int t = blockIdx.x*256 + threadIdx.x;
  if (t >= NS1C*1024) return;
  int s = t >> 10, r = t & 1023;
  int w = r >> 8, nf = (r >> 6) & 3, l = r & 63;
  int col = w*64 + nf*16 + (l & 15);
  int tap = s >> 2, cg = s & 3;
  int cb  = cg*32 + (l >> 4)*8;
  u16x8 hv, lv;
  #pragma unroll
  for (int j = 0; j < 8; ++j){
    int c = cb + j;
    int k = c*25 + tap;
    float v = W1[(size_t)k*HID + col];
    u16 h, lo; split2(v, h, lo);
    hv[j] = h; lv[j] = lo;
  }
  size_t U0 = ((((size_t)s*4 + w)*4 + nf)*2 + 0)*64 + l;
  *(u16x8*)(outp + U0*8)      = hv;
  *(u16x8*)(outp + (U0+64)*8) = lv;
}

// ---------------------------------------------------------------------------
// prep_x: Xp[c][px] = packed (hi | lo<<16) fp16 split of xi[c][px].
// Pure elementwise, float4-vectorized, fully coalesced.
// ---------------------------------------------------------------------------
__global__ __launch_bounds__(256)
void prep_x(const float* __restrict__ xi, uint32_t* __restrict__ Xp){
  size_t i = ((size_t)blockIdx.x*256 + threadIdx.x)*4;   // element index (4 per thread)
  float4 v = *(const float4*)(xi + i);
  uint32_t o0, o1, o2, o3;
  { u16 h,l; split2(v.x,h,l); o0 = (uint32_t)h | ((uint32_t)l<<16); }
  { u16 h,l; split2(v.y,h,l); o1 = (uint32_t)h | ((uint32_t)l<<16); }
  { u16 h,l; split2(v.z,h,l); o2 = (uint32_t)h | ((uint32_t)l<<16); }
  { u16 h,l; split2(v.w,h,l); o3 = (uint32_t)h | ((uint32_t)l<<16); }
  uint4 o = {o0, o1, o2, o3};
  *(uint4*)(Xp + i) = o;
}

// ---------------------------------------------------------------------------
// Layer-1 as 25-tap conv-GEMM: structurally identical to gemm_layer (proven),
// A = tap-shifted rows of Xp (8 coalesced dword loads/thread/step),
// nt = 100 K-steps. Coords handled exactly in f32 epilogue.
// 64px x 256col, 4 waves, dbuf, 1 barrier/step, 80 KB LDS -> 2 blocks/CU.
// ---------------------------------------------------------------------------
__global__ __launch_bounds__(256, 2)
void gemm_l1c(const uint32_t* __restrict__ Xp, const u16* __restrict__ Wp,
              const float* __restrict__ W1, const float* __restrict__ b1,
              uint32_t* __restrict__ hout)
{
  __shared__ __align__(16) u16 Ab[2][4096];   // 8 KB per buf
  __shared__ __align__(16) u16 Bb[2][16384];  // 32 KB per buf

  const int tid  = threadIdx.x;
  const int lane = tid & 63;
  const int wv   = tid >> 6;

  int bid = blockIdx.x;
  bid = (bid & 7)*(NBLK/8) + (bid >> 3);   // XCD-chunked swizzle (1024%8==0)
  const int pxb = bid * BPX;
  const int y   = pxb >> 8;
  const int x0  = pxb & 255;

  f32x4 acc[4][4];
  #pragma unroll
  for (int a=0;a<4;a++)
    #pragma unroll
    for (int b=0;b<4;b++) acc[a][b] = f32x4{0.f,0.f,0.f,0.f};

  uint32_t ua[8];

#define A_LOAD(S) do { \
    const int tap = (S) >> 2, cg = (S) & 3; \
    const int dy = tap/5, dx = tap - 5*dy; \
    const int yy = y + dy - 2; \
    const int xx = x0 + lane + dx - 2; \
    const bool ok = ((unsigned)yy < 256u) & ((unsigned)xx < 256u); \
    const uint32_t* xp = Xp + (((size_t)(cg*32 + wv*8))<<16) + yy*256 + xx; \
    _Pragma("unroll") \
    for (int j=0;j<8;++j) ua[j] = ok ? xp[(size_t)j<<16] : 0u; \
  } while(0)

#define A_WRITE(BUF) do { \
    u16x8 hv, lv; \
    _Pragma("unroll") \
    for (int j=0;j<8;++j){ hv[j]=(u16)(ua[j]&0xffffu); lv[j]=(u16)(ua[j]>>16); } \
    int ub = ((lane>>4)*2)*64 + wv*16 + (lane&15); \
    *(u16x8*)(&Ab[BUF][(size_t)ub*8])      = hv; \
    *(u16x8*)(&Ab[BUF][(size_t)(ub+64)*8]) = lv; \
  } while(0)

#define B_STAGE(S, BUF) do { \
    const char* _src = (const char*)Wp + (size_t)(S)*32768 + wv*8192 + lane*16; \
    char* _dst = (char*)&Bb[BUF][0] + wv*8192; \
    _Pragma("unroll") \
    for (int i=0;i<8;++i) \
      __builtin_amdgcn_global_load_lds( \
        (const __attribute__((address_space(1))) uint32_t*)(_src + i*1024), \
        (__attribute__((address_space(3))) uint32_t*)(_dst + i*1024), 16, 0, 0); \
  } while(0)

  A_LOAD(0);
  B_STAGE(0, 0);
  A_WRITE(0);
  __syncthreads();

  int cur = 0;
  for (int t = 0; t < NS1C; ++t){
    const int nxt = cur ^ 1;
    if (t+1 < NS1C){
      A_LOAD(t+1);            // coalesced, tap-shifted; hides under MFMA
      B_STAGE(t+1, nxt);      // linear global_load_lds; drained by next barrier
    }
    f16x8 ahf[4], alf[4];
    #pragma unroll
    for (int mf=0;mf<4;++mf){
      ahf[mf] = *(const f16x8*)(&Ab[cur][((size_t)((mf*2+0)*64 + lane))*8]);
      alf[mf] = *(const f16x8*)(&Ab[cur][((size_t)((mf*2+1)*64 + lane))*8]);
    }
    __builtin_amdgcn_s_setprio(1);
    #pragma unroll
    for (int nf=0;nf<4;++nf){
      f16x8 bh = *(const f16x8*)(&Bb[cur][((size_t)(((wv*4+nf)*2+0)*64 + lane))*8]);
      f16x8 bl = *(const f16x8*)(&Bb[cur][((size_t)(((wv*4+nf)*2+1)*64 + lane))*8]);
      #pragma unroll
      for (int mf=0;mf<4;++mf){
        acc[mf][nf] = __builtin_amdgcn_mfma_f32_16x16x32_f16(ahf[mf], bh, acc[mf][nf], 0,0,0);
        acc[mf][nf] = __builtin_amdgcn_mfma_f32_16x16x32_f16(alf[mf], bh, acc[mf][nf], 0,0,0);
        acc[mf][nf] = __builtin_amdgcn_mfma_f32_16x16x32_f16(ahf[mf], bl, acc[mf][nf], 0,0,0);
      }
    }
    __builtin_amdgcn_s_setprio(0);
    if (t+1 < NS1C) A_WRITE(nxt);
    __syncthreads();
    cur = nxt;
  }

  // epilogue: coords (exact f32) + bias, then h = sin(30 z) -> packed hi|lo
  float bcol[4], wyv[4], wxv[4];
  #pragma unroll
  for (int nf=0;nf<4;++nf){
    int col = wv*64 + nf*16 + (lane&15);
    bcol[nf] = b1[col];
    wyv[nf]  = W1[(size_t)3200*HID + col];
    wxv[nf]  = W1[(size_t)3201*HID + col];
  }
  const float gy = -1.f + (2.f/255.f)*(float)y;
  #pragma unroll
  for (int mf=0;mf<4;++mf)
    #pragma unroll
    for (int nf=0;nf<4;++nf)
      #pragma unroll
      for (int j=0;j<4;++j){
        int row = mf*16 + (lane>>4)*4 + j;
        float gx = -1.f + (2.f/255.f)*(float)(x0 + row);
        float z = acc[mf][nf][j] + bcol[nf] + gy*wyv[nf] + gx*wxv[nf];
        float h = sinf(30.f*z);
        u16 hh,ll; split2(h,hh,ll);
        int col = wv*64 + nf*16 + (lane&15);
        hout[(size_t)(pxb+row)*HID + col] = (uint32_t)hh | ((uint32_t)ll<<16);
      }
#undef A_LOAD
#undef A_WRITE
#undef B_STAGE
}

// ---------------------------------------------------------------------------
// Layers 2/3(+4 tail): unchanged proven structure (64px x 256col, 4 waves, dbuf).
// MODE 1: A = h; MODE 2: A = h + fused layer-4 tail.
// ---------------------------------------------------------------------------
template<int MODE>
__global__ __launch_bounds__(256, 2)
void gemm_layer(const uint32_t* __restrict__ hin,
                const u16* __restrict__ Wp, const float* __restrict__ bias,
                uint32_t* __restrict__ hout, const float* __restrict__ W4,
                const float* __restrict__ b4, float* __restrict__ out, int nt)
{
  __shared__ __align__(16) u16 Ab[2][4096];
  __shared__ __align__(16) u16 Bb[2][16384];

  const int tid  = threadIdx.x;
  const int lane = tid & 63;
  const int wv   = tid >> 6;

  int bid = blockIdx.x;
  bid = (bid & 7)*(NBLK/8) + (bid >> 3);
  const int pxb = bid * BPX;

  f32x4 acc[4][4];
  #pragma unroll
  for (int a=0;a<4;a++)
    #pragma unroll
    for (int b=0;b<4;b++) acc[a][b] = f32x4{0.f,0.f,0.f,0.f};

  uint32_t ua[8];

#define A_LOAD(S) do { \
    const uint32_t* hp = hin + (size_t)(pxb + lane)*HID + (S)*32 + wv*8; \
    uint4 a0 = *(const uint4*)hp; \
    uint4 a1 = *(const uint4*)(hp+4); \
    ua[0]=a0.x; ua[1]=a0.y; ua[2]=a0.z; ua[3]=a0.w; \
    ua[4]=a1.x; ua[5]=a1.y; ua[6]=a1.z; ua[7]=a1.w; \
  } while(0)

#define A_WRITE(BUF) do { \
    u16x8 hv, lv; \
    _Pragma("unroll") \
    for (int j=0;j<8;++j){ hv[j]=(u16)(ua[j]&0xffffu); lv[j]=(u16)(ua[j]>>16); } \
    int ub = ((lane>>4)*2)*64 + wv*16 + (lane&15); \
    *(u16x8*)(&Ab[BUF][(size_t)ub*8])      = hv; \
    *(u16x8*)(&Ab[BUF][(size_t)(ub+64)*8]) = lv; \
  } while(0)

#define B_STAGE(S, BUF) do { \
    const char* _src = (const char*)Wp + (size_t)(S)*32768 + wv*8192 + lane*16; \
    char* _dst = (char*)&Bb[BUF][0] + wv*8192; \
    _Pragma("unroll") \
    for (int i=0;i<8;++i) \
      __builtin_amdgcn_global_load_lds( \
        (const __attribute__((address_space(1))) uint32_t*)(_src + i*1024), \
        (__attribute__((address_space(3))) uint32_t*)(_dst + i*1024), 16, 0, 0); \
  } while(0)

  A_LOAD(0);
  B_STAGE(0, 0);
  A_WRITE(0);
  __syncthreads();

  int cur = 0;
  for (int t = 0; t < nt; ++t){
    const int nxt = cur ^ 1;
    if (t+1 < nt){
      A_LOAD(t+1);
      B_STAGE(t+1, nxt);
    }
    f16x8 ahf[4], alf[4];
    #pragma unroll
    for (int mf=0;mf<4;++mf){
      ahf[mf] = *(const f16x8*)(&Ab[cur][((size_t)((mf*2+0)*64 + lane))*8]);
      alf[mf] = *(const f16x8*)(&Ab[cur][((size_t)((mf*2+1)*64 + lane))*8]);
    }
    __builtin_amdgcn_s_setprio(1);
    #pragma unroll
    for (int nf=0;nf<4;++nf){
      f16x8 bh = *(const f16x8*)(&Bb[cur][((size_t)(((wv*4+nf)*2+0)*64 + lane))*8]);
      f16x8 bl = *(const f16x8*)(&Bb[cur][((size_t)(((wv*4+nf)*2+1)*64 + lane))*8]);
      #pragma unroll
      for (int mf=0;mf<4;++mf){
        acc[mf][nf] = __builtin_amdgcn_mfma_f32_16x16x32_f16(ahf[mf], bh, acc[mf][nf], 0,0,0);
        acc[mf][nf] = __builtin_amdgcn_mfma_f32_16x16x32_f16(alf[mf], bh, acc[mf][nf], 0,0,0);
        acc[mf][nf] = __builtin_amdgcn_mfma_f32_16x16x32_f16(ahf[mf], bl, acc[mf][nf], 0,0,0);
      }
    }
    __builtin_amdgcn_s_setprio(0);
    if (t+1 < nt) A_WRITE(nxt);
    __syncthreads();
    cur = nxt;
  }

  float bcol[4];
  #pragma unroll
  for (int nf=0;nf<4;++nf) bcol[nf] = bias[wv*64 + nf*16 + (lane&15)];

  if (MODE != 2){
    #pragma unroll
    for (int mf=0;mf<4;++mf)
      #pragma unroll
      for (int nf=0;nf<4;++nf)
        #pragma unroll
        for (int j=0;j<4;++j){
          float z = acc[mf][nf][j] + bcol[nf];
          float h = sinf(30.f*z);
          u16 hh,ll; split2(h,hh,ll);
          int row = mf*16 + (lane>>4)*4 + j;
          int col = wv*64 + nf*16 + (lane&15);
          hout[(size_t)(pxb+row)*HID + col] = (uint32_t)hh | ((uint32_t)ll<<16);
        }
  } else {
    float (*red)[64][3] = (float(*)[64][3])(void*)&Ab[0][0];
    float w4v[4][3];
    #pragma unroll
    for (int nf=0;nf<4;++nf){
      int col = wv*64 + nf*16 + (lane&15);
      w4v[nf][0]=W4[col*3+0]; w4v[nf][1]=W4[col*3+1]; w4v[nf][2]=W4[col*3+2];
    }
    #pragma unroll
    for (int mf=0;mf<4;++mf)
      #pragma unroll
      for (int j=0;j<4;++j){
        float s0=0.f,s1=0.f,s2=0.f;
        #pragma unroll
        for (int nf=0;nf<4;++nf){
          float h = sinf(30.f*(acc[mf][nf][j] + bcol[nf]));
          s0 += h*w4v[nf][0]; s1 += h*w4v[nf][1]; s2 += h*w4v[nf][2];
        }
        #pragma unroll
        for (int m=1;m<16;m<<=1){
          s0 += __shfl_xor(s0, m);
          s1 += __shfl_xor(s1, m);
          s2 += __shfl_xor(s2, m);
        }
        if ((lane & 15) == 0){
          int row = mf*16 + (lane>>4)*4 + j;
          red[wv][row][0]=s0; red[wv][row][1]=s1; red[wv][row][2]=s2;
        }
      }
    __syncthreads();
    if (tid < 192){
      int px = tid & 63, c = tid >> 6;
      float v = red[0][px][c]+red[1][px][c]+red[2][px][c]+red[3][px][c] + b4[c];
      out[(size_t)c*NPX + pxb + px] = v;
    }
  }
#undef A_LOAD
#undef A_WRITE
#undef B_STAGE
}

// ---------------------------------------------------------------------------
extern "C" void kernel_launch(void* const* d_in, const int* in_sizes, int n_in,
                              void* d_out, int out_size, void* d_ws, size_t ws_size,
                              hipStream_t stream) {
  const float* xi = (const float*)d_in[0];
  const float* W1 = (const float*)d_in[1];
  const float* b1 = (const float*)d_in[2];
  const float* W2 = (const float*)d_in[3];
  const float* b2 = (const float*)d_in[4];
  const float* W3 = (const float*)d_in[5];
  const float* b3 = (const float*)d_in[6];
  const float* W4 = (const float*)d_in[7];
  const float* b4 = (const float*)d_in[8];
  float* out = (float*)d_out;

  char* ws = (char*)d_ws;
  u16* W1c = (u16*)(ws + OFF_W1C);
  u16* W2p = (u16*)(ws + OFF_W2);
  u16* W3p = (u16*)(ws + OFF_W3);
  uint32_t* h  = (uint32_t*)(ws + OFF_H);
  uint32_t* Xp = (uint32_t*)(ws + OFF_X);

  prep_w1c<<<NS1C*4, 256, 0, stream>>>(W1, W1c);          // 400 blocks
  prep_w<<<NS2*4, 256, 0, stream>>>(W2, HID, NS2, W2p);
  prep_w<<<NS2*4, 256, 0, stream>>>(W3, HID, NS2, W3p);
  prep_x<<<(128*NPX)/(256*4), 256, 0, stream>>>(xi, Xp);  // 8192 blocks

  dim3 grid(NBLK), block(256);
  gemm_l1c<<<grid, block, 0, stream>>>(Xp, W1c, W1, b1, h);
  gemm_layer<1><<<grid, block, 0, stream>>>(h, W2p, b2, h,
                                            nullptr, nullptr, nullptr, NS2);
  gemm_layer<2><<<grid, block, 0, stream>>>(h, W3p, b3, nullptr,
                                            W4, b4, out, NS2);
}